// Round 2
// baseline (449.556 us; speedup 1.0000x reference)
//
#include <hip/hip_runtime.h>

// LengthRegulator, two-kernel structure.
// x (32,1024,384) f32, duration (32,1024) i32, T=8192.
// out0: (32, 8192, 384) f32 gathered+masked;  out1: mel_len (32,) as f32.
//
// Round 2 change: A/B test — plain (L2-cached) stores instead of
// __builtin_nontemporal_store. The harness's own fillBuffer hits 6.36 TB/s
// with cached stores; both NT-store rounds sat at ~2.4 TB/s effective
// regardless of all other structure. Everything else identical to round 1.
//
// Kernel A (32 blocks x 256 thr): per-batch inclusive csum of duration into
//   g_csum + g_mel[b] + mel_out[b]. ~2-3 us.
// Kernel B (4096 blocks x 256 thr, XCD-swizzled, ROWS=64 output rows/block):
//   - fully-masked window (t0 >= mel_len, ~56% of blocks): pure zero-store
//     loop — no LDS, no barriers, no loads.
//   - valid window: csum slice load (no scan), run-intersection scatter into
//     src[] in LDS (one barrier), streaming gather with 16B loads + stores.

#define BATCH 32
#define SRC_S 1024
#define DIM   384
#define ROWS  64          // output rows per gather block
#define C4    (DIM / 4)   // 96 16B-vectors per row
#define NXCD  8

typedef float f32x4 __attribute__((ext_vector_type(4)));
typedef int   i32x4 __attribute__((ext_vector_type(4)));

__device__ int g_csum[BATCH * SRC_S];  // inclusive csum per batch
__device__ int g_mel[BATCH];           // csum[b][S-1]

// ---------------- Kernel A: csum + mel_len ----------------
__global__ __launch_bounds__(256)
void lr_csum_kernel(const int* __restrict__ duration, float* __restrict__ mel_out) {
    __shared__ int wsum[4];
    const int b = blockIdx.x;
    const int tid = threadIdx.x;
    const int lane = tid & 63;
    const int wid = tid >> 6;

    const i32x4 d = ((const i32x4*)(duration + b * SRC_S))[tid];
    const int s0 = d.x;
    const int s1 = s0 + d.y;
    const int s2 = s1 + d.z;
    const int s3 = s2 + d.w;               // thread-local inclusive sums
    int tot = s3;
    #pragma unroll
    for (int off = 1; off < 64; off <<= 1) {   // wave inclusive scan
        const int n = __shfl_up(tot, off, 64);
        if (lane >= off) tot += n;
    }
    if (lane == 63) wsum[wid] = tot;
    __syncthreads();
    int base = 0;
    #pragma unroll
    for (int w = 0; w < 3; ++w) base += (w < wid) ? wsum[w] : 0;
    const int pre = base + tot - s3;       // thread's exclusive prefix

    i32x4 c;
    c.x = pre + s0; c.y = pre + s1; c.z = pre + s2; c.w = pre + s3;
    ((i32x4*)(g_csum + b * SRC_S))[tid] = c;

    if (tid == 255) {                      // last thread holds the total
        const int mel = pre + s3;
        g_mel[b] = mel;
        mel_out[b] = (float)mel;           // exact in f32 (<= 7168)
    }
}

// ---------------- Kernel B: gather / zero-fill ----------------
__global__ __launch_bounds__(256)
void lr_gather_kernel(const f32x4* __restrict__ x4, f32x4* __restrict__ out4, int T) {
    // XCD-aware swizzle: 4 whole batches per XCD, consecutive windows per batch.
    const int l = blockIdx.x;              // 0 .. 4095
    const int xcd = l & (NXCD - 1);
    const int j = l >> 3;                  // 0 .. 511
    const int wpb = 8192 / ROWS;           // 128 windows per batch
    const int b = xcd + NXCD * (j >> 7);   // 0 .. 31
    const int t0 = (j & (wpb - 1)) * ROWS; // 0 .. 8128
    const int tid = threadIdx.x;

    f32x4* __restrict__ ob = out4 + ((size_t)b * T + t0) * C4;
    const int mel = g_mel[b];              // uniform 4B, L2-hot

    if (t0 >= mel) {
        // Fully-masked window: pure streaming zero-fill (cached stores).
        const f32x4 z = (f32x4)(0.f);
        #pragma unroll
        for (int k = 0; k < (ROWS * C4) / 256; ++k)   // 24 iterations
            ob[tid + k * 256] = z;
        return;
    }

    __shared__ int src[ROWS];
    // Issue csum loads before touching LDS so latency hides under the barrier.
    const int* __restrict__ cb = g_csum + b * SRC_S;
    const i32x4 c = ((const i32x4*)cb)[tid];
    const int prev = (tid == 0) ? 0 : cb[4 * tid - 1];

    if (tid < ROWS) src[tid] = -1;         // default: masked (zero) row
    __syncthreads();

    // Run-intersection scatter: thread's 4 runs vs window [t0, t0+ROWS).
    const int st[4] = {prev, c.x, c.y, c.z};   // run starts
    const int en[4] = {c.x, c.y, c.z, c.w};    // run ends
    #pragma unroll
    for (int e = 0; e < 4; ++e) {
        const int lo = (st[e] > t0) ? st[e] : t0;
        const int hi = (en[e] < t0 + ROWS) ? en[e] : (t0 + ROWS);
        const int off = (tid * 4 + e) * C4;    // pre-multiplied vector offset
        for (int t = lo; t < hi; ++t) src[t - t0] = off;
    }
    __syncthreads();

    // Streaming gather: 16B x-loads (L2-resident), plain 16B stores.
    const f32x4* __restrict__ xb = x4 + (size_t)b * SRC_S * C4;
    #pragma unroll
    for (int k = 0; k < (ROWS * C4) / 256; ++k) {   // 24 iterations
        const int i = tid + k * 256;
        const int row = i / C4;                      // const-div -> magic mul
        const int col = i - row * C4;
        const int o = src[row];                      // LDS broadcast
        f32x4 v = (f32x4)(0.f);
        if (o >= 0) v = xb[o + col];
        ob[i] = v;                                   // cached store
    }
}

extern "C" void kernel_launch(void* const* d_in, const int* in_sizes, int n_in,
                              void* d_out, int out_size, void* d_ws, size_t ws_size,
                              hipStream_t stream) {
    const float* x = (const float*)d_in[0];
    const int* duration = (const int*)d_in[1];
    const int T = (out_size - BATCH) / (BATCH * DIM);   // 8192

    float* out = (float*)d_out;
    float* mel_out = out + (size_t)BATCH * T * DIM;     // out1 region

    lr_csum_kernel<<<BATCH, 256, 0, stream>>>(duration, mel_out);

    const int nblocks = BATCH * (T / ROWS);             // 4096
    lr_gather_kernel<<<nblocks, 256, 0, stream>>>((const f32x4*)x,
                                                  (f32x4*)out, T);
}

// Round 3
// 433.856 us; speedup vs baseline: 1.0362x; 1.0362x over previous
//
#include <hip/hip_runtime.h>

// LengthRegulator, round 3: run-based scatter (source-run decomposition).
// x (32,1024,384) f32, duration (32,1024) i32, T=8192.
// out0: (32, 8192, 384) f32 gathered+masked;  out1: mel_len (32,) as f32.
//
// Theory: rounds 0-2 were invariant (~190 us residual) because the valid-
// region store stream was 1:1 dependent on conditional global loads. This
// version makes the store stream memcpy-shaped:
//   Kernel A (32 x 256): per-batch csum of duration -> g_csum, g_mel, mel_out.
//   Kernel B (4096 + 32768 blocks x 192 thr):
//     - blocks [0, 4096): zero-fill of the masked tail. Each owns a 64-row
//       window; writes zeros to rows [max(t0,mel), t0+64). Pure store loop.
//     - blocks [4096, ...): one block per (batch, source row). Loads the
//       1536 B x-row ONCE (issued before csum is even read), then stores it
//       duration[b,i] (0..7) times to contiguous output rows. No LDS, no
//       barrier, no conditional loads; all control flow block-uniform.
// x read exactly once (48 MB); writes 402 MB; runs partition [0, mel) so
// every output row is written exactly once.

#define BATCH 32
#define SRC_S 1024
#define DIM   384
#define C2    (DIM / 2)   // 192 f32x2 per row
#define ZROWS 64          // rows per zero-fill block

typedef float f32x2 __attribute__((ext_vector_type(2)));
typedef int   i32x4 __attribute__((ext_vector_type(4)));

__device__ int g_csum[BATCH * SRC_S];  // inclusive csum per batch
__device__ int g_mel[BATCH];           // csum[b][S-1]

// ---------------- Kernel A: csum + mel_len ----------------
__global__ __launch_bounds__(256)
void lr_csum_kernel(const int* __restrict__ duration, float* __restrict__ mel_out) {
    __shared__ int wsum[4];
    const int b = blockIdx.x;
    const int tid = threadIdx.x;
    const int lane = tid & 63;
    const int wid = tid >> 6;

    const i32x4 d = ((const i32x4*)(duration + b * SRC_S))[tid];
    const int s0 = d.x;
    const int s1 = s0 + d.y;
    const int s2 = s1 + d.z;
    const int s3 = s2 + d.w;               // thread-local inclusive sums
    int tot = s3;
    #pragma unroll
    for (int off = 1; off < 64; off <<= 1) {   // wave inclusive scan
        const int n = __shfl_up(tot, off, 64);
        if (lane >= off) tot += n;
    }
    if (lane == 63) wsum[wid] = tot;
    __syncthreads();
    int base = 0;
    #pragma unroll
    for (int w = 0; w < 3; ++w) base += (w < wid) ? wsum[w] : 0;
    const int pre = base + tot - s3;       // thread's exclusive prefix

    i32x4 c;
    c.x = pre + s0; c.y = pre + s1; c.z = pre + s2; c.w = pre + s3;
    ((i32x4*)(g_csum + b * SRC_S))[tid] = c;

    if (tid == 255) {                      // last thread holds the total
        const int mel = pre + s3;
        g_mel[b] = mel;
        mel_out[b] = (float)mel;           // exact in f32 (<= 7168)
    }
}

// ---------------- Kernel B: zero-fill + run-copy ----------------
__global__ __launch_bounds__(192)
void lr_scatter_kernel(const f32x2* __restrict__ x2, f32x2* __restrict__ out2,
                       int T) {
    const int l = blockIdx.x;
    const int tid = threadIdx.x;           // 0..191, one f32x2 column
    const int nzf = BATCH * (T / ZROWS);   // 4096 zero-fill blocks, first

    if (l < nzf) {
        // ---- masked-tail zero-fill: rows [max(t0,mel), t0+ZROWS) ----
        const int nw = T / ZROWS;          // 128 windows per batch
        const int b = l / nw;
        const int t0 = (l - b * nw) * ZROWS;
        const int mel = g_mel[b];          // uniform 4B, L2-hot
        const int start = (mel > t0) ? mel : t0;
        const int end = t0 + ZROWS;
        if (start >= end) return;          // window entirely valid -> no-op
        const f32x2 zz = {0.f, 0.f};
        f32x2* __restrict__ o = out2 + ((size_t)b * T + start) * C2 + tid;
        for (int m = start; m < end; ++m) { *o = zz; o += C2; }
        return;
    }

    // ---- run-copy: one block per (batch, source row) ----
    const int r = l - nzf;                 // 0 .. 32767
    const int b = r >> 10;
    const int i = r & (SRC_S - 1);

    // Issue the x-row load immediately; independent of the csum loads.
    const f32x2 v = x2[(size_t)(b * SRC_S + i) * C2 + tid];

    const int* __restrict__ cb = g_csum + b * SRC_S;   // scalar loads, L2-hot
    const int prev = (i == 0) ? 0 : cb[i - 1];
    const int cur = cb[i];                 // run = [prev, cur), 0..7 rows

    f32x2* __restrict__ o = out2 + ((size_t)b * T + prev) * C2 + tid;
    for (int m = prev; m < cur; ++m) { *o = v; o += C2; }  // burst stores
}

extern "C" void kernel_launch(void* const* d_in, const int* in_sizes, int n_in,
                              void* d_out, int out_size, void* d_ws, size_t ws_size,
                              hipStream_t stream) {
    const float* x = (const float*)d_in[0];
    const int* duration = (const int*)d_in[1];
    const int T = (out_size - BATCH) / (BATCH * DIM);   // 8192

    float* out = (float*)d_out;
    float* mel_out = out + (size_t)BATCH * T * DIM;     // out1 region

    lr_csum_kernel<<<BATCH, 256, 0, stream>>>(duration, mel_out);

    const int nblocks = BATCH * (T / ZROWS) + BATCH * SRC_S;  // 4096 + 32768
    lr_scatter_kernel<<<nblocks, 192, 0, stream>>>((const f32x2*)x,
                                                   (f32x2*)out, T);
}